// Round 3
// baseline (4407.642 us; speedup 1.0000x reference)
//
#include <hip/hip_runtime.h>

typedef __attribute__((ext_vector_type(8))) short short8;
typedef __attribute__((ext_vector_type(4))) float f32x4;

// ---------------- ws layout (bytes) ----------------
// rcp  : float [8][512]                        @ 0         (16384)
// wpre : bf16  [c=8][t=9][kb=8][co=512][8]     @ 16384     (4718592)
// xm   : bf16  [b=8][g=64][hp=34][col=34][8]   @ 4734976   (9469952)  (h padded: hp=0 and hp=33 are zero rows)
#define RCP_OFF   0
#define WPRE_OFF  16384
#define XM_OFF    4734976

__device__ __forceinline__ unsigned short f2bf(float f) {
  unsigned int u = __float_as_uint(f);
  u += 0x7FFFu + ((u >> 16) & 1u);       // round-to-nearest-even
  return (unsigned short)(u >> 16);
}

__device__ __forceinline__ void gload_lds16(const void* g, void* l) {
  __builtin_amdgcn_global_load_lds(
      (__attribute__((address_space(1))) void*)g,
      (__attribute__((address_space(3))) void*)l, 16, 0, 0);
}

// ---------------- prep 1: demod rcp[b][o], 1 wave per o ----------------
__global__ void xs_kernel(const float* __restrict__ w, const float* __restrict__ ys,
                          float* __restrict__ rcp) {
  int o = blockIdx.x;
  int lane = threadIdx.x;                 // 64
  const float* wp = w + (size_t)o * 4608 + (size_t)lane * 72;  // 8 ci x 9 taps
  const float scale2 = 1.0f / 4608.0f;
  float w2[8];
#pragma unroll
  for (int j = 0; j < 8; ++j) {
    float s = 0.f;
#pragma unroll
    for (int k = 0; k < 9; ++k) { float v = wp[j * 9 + k]; s += v * v; }
    w2[j] = s * scale2;
  }
#pragma unroll
  for (int b = 0; b < 8; ++b) {
    float p = 0.f;
#pragma unroll
    for (int j = 0; j < 8; ++j) {
      float y = ys[b * 512 + lane * 8 + j];
      p += y * y * w2[j];
    }
#pragma unroll
    for (int off = 32; off > 0; off >>= 1) p += __shfl_down(p, off);
    if (lane == 0) rcp[b * 512 + o] = 1.0f / sqrtf(p + 1e-8f);
  }
}

// ---------------- prep 2: modulated x -> bf16, channel-grouped, padded h & w ----------------
__global__ void xm_kernel(const float* __restrict__ x, const float* __restrict__ ys,
                          unsigned short* __restrict__ xm) {
  int bid = blockIdx.x;            // [b(8)][h(32)][half(2)]
  int half = bid & 1;
  int h = (bid >> 1) & 31;
  int b = bid >> 6;
  int tid = threadIdx.x;
  __shared__ float tile[256][33];
  int ci0 = half * 256;
#pragma unroll
  for (int r = 0; r < 32; ++r) {
    int ci = r * 8 + (tid >> 5);
    int wcol = tid & 31;
    float v = x[(((size_t)b * 512 + ci0 + ci) * 32 + h) * 32 + wcol];
    tile[ci][wcol] = v * ys[b * 512 + ci0 + ci];
  }
  __syncthreads();
  int g0 = half * 32;
  for (int r = 0; r < 5; ++r) {
    int idx = r * 256 + tid;                     // [gl(32)][col(34)]
    if (idx < 1088) {
      int gl = idx / 34;
      int col = idx - gl * 34;
      short8 v = {0,0,0,0,0,0,0,0};
      if (col != 0 && col != 33) {
        int wcol = col - 1;
#pragma unroll
        for (int j = 0; j < 8; ++j)
          v[j] = (short)f2bf(tile[gl * 8 + j][wcol]);
      }
      size_t off = ((((size_t)b * 64 + g0 + gl) * 34 + (h + 1)) * 34 + col) * 8;
      *reinterpret_cast<short8*>(xm + off) = v;
    }
  }
  // zero pad rows hp=0 (above h=0) and hp=33 (below h=31)
  if (h == 0 || h == 31) {
    int hp = (h == 0) ? 0 : 33;
    for (int r = 0; r < 5; ++r) {
      int idx = r * 256 + tid;
      if (idx < 1088) {
        int gl = idx / 34;
        int col = idx - gl * 34;
        short8 z = {0,0,0,0,0,0,0,0};
        size_t off = ((((size_t)b * 64 + g0 + gl) * 34 + hp) * 34 + col) * 8;
        *reinterpret_cast<short8*>(xm + off) = z;
      }
    }
  }
}

// ---------------- prep 3: scaled weight -> bf16 fragment layout (coalesced-ish reads) ----------------
__global__ void wpre_kernel(const float* __restrict__ w, unsigned short* __restrict__ wpre) {
  int kb = blockIdx.x & 7;         // grid 64 = [c(8)][kb(8)]
  int c  = blockIdx.x >> 3;
  int co = threadIdx.x;            // 512
  int ci0 = c * 64 + kb * 8;
  const float* wp = w + (size_t)co * 4608 + (size_t)ci0 * 9;   // 72 contiguous floats
  float v[72];
  const f32x4* wp4 = reinterpret_cast<const f32x4*>(wp);
#pragma unroll
  for (int i = 0; i < 18; ++i) {
    f32x4 q = wp4[i];
    v[i * 4 + 0] = q[0]; v[i * 4 + 1] = q[1]; v[i * 4 + 2] = q[2]; v[i * 4 + 3] = q[3];
  }
  const float scale = 1.4731391274719738e-02f;   // (512*9)^-0.5
#pragma unroll
  for (int t = 0; t < 9; ++t) {
    short8 s;
#pragma unroll
    for (int j = 0; j < 8; ++j) s[j] = (short)f2bf(scale * v[j * 9 + t]);
    *reinterpret_cast<short8*>(wpre + ((((size_t)c * 9 + t) * 8 + kb) * 512 + co) * 8) = s;
  }
}

// ---------------- main: implicit-GEMM direct conv ----------------
// grid 256 = [sp(64)=b*8+hg][cog(4)], block 512 = 8 waves (wr,wc 2x2 spatial, kp 2-way K-split)
// A-frags: registers, loaded straight from wpre (L2/L1), double-buffered 1 tap ahead.
//   Buffer index MUST be ct&1 (linear tap counter) — t&1 breaks parity at chunk
//   boundaries (t: 8 -> 0 while prefetch went to tb^1), which was R2's bug.
// B-frags: LDS xbuf, double-buffered per ci-chunk via async global_load_lds (lane-linear).
// xbuf[2][kb=8][rr=6][col=34][8] bf16 = 2 x 26112 B. One barrier per chunk.
__global__ __launch_bounds__(512, 2) void conv_main(
    const unsigned short* __restrict__ wpre,
    const unsigned short* __restrict__ xm,
    const float* __restrict__ rcp,
    const float* __restrict__ bias,
    float* __restrict__ out)
{
  __shared__ __align__(16) char smem[52224];

  int bid = blockIdx.x;
  int cog = bid & 3;
  int sp = bid >> 2;
  int b = sp >> 3;
  int hg = sp & 7;
  int tid = threadIdx.x;
  int lane = tid & 63;
  int wv = tid >> 6;                // 0..7
  int wc = wv & 1;
  int wr = (wv >> 1) & 1;
  int kp = wv >> 2;                 // K-split half
  int l15 = lane & 15, l4 = lane >> 4;

  f32x4 acc[4][4];
#pragma unroll
  for (int i = 0; i < 4; ++i)
#pragma unroll
    for (int j = 0; j < 4; ++j) { f32x4 z = {0.f,0.f,0.f,0.f}; acc[i][j] = z; }

  const unsigned short* xmb = xm + (size_t)b * (64 * 34 * 34 * 8);
  // this thread's A-frag base: element (kb=kp*4+l4, co = cog*128 + wr*64 + l15)
  const unsigned short* wbase =
      wpre + ((size_t)(kp * 4 + l4) * 512 + cog * 128 + wr * 64 + l15) * 8;

  auto stageX = [&](int c, int buf) {
    char* xb = smem + buf * 26112;
#pragma unroll
    for (int r = 0; r < 4; ++r) {
      int idx = r * 512 + tid;                 // [kb(8)][rr(6)][col(34)] = 1632 chunks
      if (idx < 1632) {
        int kb = idx / 204;
        int rem = idx - kb * 204;
        int rr = rem / 34;
        int col = rem - rr * 34;
        const unsigned short* src =
            xmb + (((size_t)(c * 8 + kb) * 34 + hg * 4 + rr) * 34 + col) * 8;
        gload_lds16(src, xb + idx * 16);
      }
    }
  };

  short8 areg[2][4];
  auto loadA = [&](int ct, short8* a) {
    const unsigned short* p = wbase + (size_t)ct * 32768;
#pragma unroll
    for (int mi = 0; mi < 4; ++mi)
      a[mi] = *reinterpret_cast<const short8*>(p + mi * 128);
  };

  // prologue
  stageX(0, 0);
  loadA(0, areg[0]);
  __syncthreads();

  for (int c = 0; c < 8; ++c) {
    const char* xb = smem + (c & 1) * 26112;
    if (c < 7) stageX(c + 1, (c + 1) & 1);     // async, drains at chunk-end barrier
#pragma unroll
    for (int t = 0; t < 9; ++t) {
      int ct = c * 9 + t;
      int tb = ct & 1;                          // linear-parity double buffer (fix)
      if (ct < 71) loadA(ct + 1, areg[tb ^ 1]); // prefetch next tap's A into regs
      int kh = t / 3, kw = t % 3;
#pragma unroll
      for (int nj = 0; nj < 4; ++nj) {
        int row4 = wc * 2 + (nj >> 1);
        int bo = (kp * 4 + l4) * 3264 + (row4 + kh) * 544 + ((nj & 1) * 16 + l15 + kw) * 16;
        short8 bfrag = *reinterpret_cast<const short8*>(xb + bo);
#pragma unroll
        for (int mi = 0; mi < 4; ++mi)
          acc[mi][nj] = __builtin_amdgcn_mfma_f32_16x16x32_bf16(areg[tb][mi], bfrag, acc[mi][nj], 0, 0, 0);
      }
    }
    __syncthreads();
  }

  // ---- K-split reduction (kp1 -> LDS -> kp0) ----
#pragma unroll
  for (int p = 0; p < 2; ++p) {
    if (kp == 1 && wr == p) {
#pragma unroll
      for (int mi = 0; mi < 4; ++mi)
#pragma unroll
        for (int nj = 0; nj < 4; ++nj)
          *reinterpret_cast<f32x4*>(smem + wc * 16384 + (mi * 4 + nj) * 1024 + lane * 16) = acc[mi][nj];
    }
    __syncthreads();
    if (kp == 0 && wr == p) {
#pragma unroll
      for (int mi = 0; mi < 4; ++mi)
#pragma unroll
        for (int nj = 0; nj < 4; ++nj) {
          f32x4 v = *reinterpret_cast<const f32x4*>(smem + wc * 16384 + (mi * 4 + nj) * 1024 + lane * 16);
          acc[mi][nj] = acc[mi][nj] + v;
        }
    }
    __syncthreads();
  }

  // ---- epilogue: demod + bias, fp32 NCHW store ----
  if (kp == 0) {
    const float* rcpb = rcp + b * 512;
#pragma unroll
    for (int mi = 0; mi < 4; ++mi) {
      int ob = cog * 128 + wr * 64 + mi * 16 + l4 * 4;
      float rc[4], bi[4];
#pragma unroll
      for (int j = 0; j < 4; ++j) { rc[j] = rcpb[ob + j]; bi[j] = bias[ob + j]; }
#pragma unroll
      for (int nj = 0; nj < 4; ++nj) {
        int row4 = wc * 2 + (nj >> 1);
        int wcol = (nj & 1) * 16 + l15;
        int h = hg * 4 + row4;
#pragma unroll
        for (int j = 0; j < 4; ++j)
          out[(((size_t)b * 512 + ob + j) * 32 + h) * 32 + wcol] = acc[mi][nj][j] * rc[j] + bi[j];
      }
    }
  }
}

extern "C" void kernel_launch(void* const* d_in, const int* in_sizes, int n_in,
                              void* d_out, int out_size, void* d_ws, size_t ws_size,
                              hipStream_t stream) {
  const float* x    = (const float*)d_in[0];
  const float* ys   = (const float*)d_in[1];
  const float* w    = (const float*)d_in[2];
  const float* bias = (const float*)d_in[3];
  float* out = (float*)d_out;
  char* ws = (char*)d_ws;
  float* rcp = (float*)(ws + RCP_OFF);
  unsigned short* wpre = (unsigned short*)(ws + WPRE_OFF);
  unsigned short* xm   = (unsigned short*)(ws + XM_OFF);

  xs_kernel<<<512, 64, 0, stream>>>(w, ys, rcp);
  wpre_kernel<<<64, 512, 0, stream>>>(w, wpre);
  xm_kernel<<<512, 256, 0, stream>>>(x, ys, xm);
  conv_main<<<256, 512, 0, stream>>>(wpre, xm, rcp, bias, out);
}

// Round 4
// 77.662 us; speedup vs baseline: 56.7539x; 56.7539x over previous
//
#include <hip/hip_runtime.h>

typedef __attribute__((ext_vector_type(8))) short short8;
typedef __attribute__((ext_vector_type(4))) float f32x4;

// ---------------- ws layout (bytes) ----------------
// rcp  : float [8][512]                        @ 0         (16384)
// wpre : bf16  [c=8][t=9][kb=8][co=512][8]     @ 16384     (4718592)
// xm   : bf16  [b=8][g=64][hp=34][col=34][8]   @ 4734976   (9469952)  (hp=0 / hp=33 are zero rows)
#define RCP_OFF   0
#define WPRE_OFF  16384
#define XM_OFF    4734976

__device__ __forceinline__ unsigned short f2bf(float f) {
  unsigned int u = __float_as_uint(f);
  u += 0x7FFFu + ((u >> 16) & 1u);       // round-to-nearest-even
  return (unsigned short)(u >> 16);
}

__device__ __forceinline__ void gload_lds16(const void* g, void* l) {
  __builtin_amdgcn_global_load_lds(
      (__attribute__((address_space(1))) void*)g,
      (__attribute__((address_space(3))) void*)l, 16, 0, 0);
}

// ---------------- prep 1: demod rcp[b][o], 1 wave per o ----------------
__global__ void xs_kernel(const float* __restrict__ w, const float* __restrict__ ys,
                          float* __restrict__ rcp) {
  int o = blockIdx.x;
  int lane = threadIdx.x;                 // 64
  const float* wp = w + (size_t)o * 4608 + (size_t)lane * 72;  // 8 ci x 9 taps
  const float scale2 = 1.0f / 4608.0f;
  float w2[8];
#pragma unroll
  for (int j = 0; j < 8; ++j) {
    float s = 0.f;
#pragma unroll
    for (int k = 0; k < 9; ++k) { float v = wp[j * 9 + k]; s += v * v; }
    w2[j] = s * scale2;
  }
#pragma unroll
  for (int b = 0; b < 8; ++b) {
    float p = 0.f;
#pragma unroll
    for (int j = 0; j < 8; ++j) {
      float y = ys[b * 512 + lane * 8 + j];
      p += y * y * w2[j];
    }
#pragma unroll
    for (int off = 32; off > 0; off >>= 1) p += __shfl_down(p, off);
    if (lane == 0) rcp[b * 512 + o] = 1.0f / sqrtf(p + 1e-8f);
  }
}

// ---------------- prep 2: modulated x -> bf16, channel-grouped, padded h & w ----------------
__global__ void xm_kernel(const float* __restrict__ x, const float* __restrict__ ys,
                          unsigned short* __restrict__ xm) {
  int bid = blockIdx.x;            // [b(8)][h(32)][half(2)]
  int half = bid & 1;
  int h = (bid >> 1) & 31;
  int b = bid >> 6;
  int tid = threadIdx.x;
  __shared__ float tile[256][33];
  int ci0 = half * 256;
#pragma unroll
  for (int r = 0; r < 32; ++r) {
    int ci = r * 8 + (tid >> 5);
    int wcol = tid & 31;
    float v = x[(((size_t)b * 512 + ci0 + ci) * 32 + h) * 32 + wcol];
    tile[ci][wcol] = v * ys[b * 512 + ci0 + ci];
  }
  __syncthreads();
  int g0 = half * 32;
  for (int r = 0; r < 5; ++r) {
    int idx = r * 256 + tid;                     // [gl(32)][col(34)]
    if (idx < 1088) {
      int gl = idx / 34;
      int col = idx - gl * 34;
      short8 v = {0,0,0,0,0,0,0,0};
      if (col != 0 && col != 33) {
        int wcol = col - 1;
#pragma unroll
        for (int j = 0; j < 8; ++j)
          v[j] = (short)f2bf(tile[gl * 8 + j][wcol]);
      }
      size_t off = ((((size_t)b * 64 + g0 + gl) * 34 + (h + 1)) * 34 + col) * 8;
      *reinterpret_cast<short8*>(xm + off) = v;
    }
  }
  // zero pad rows hp=0 (above h=0) and hp=33 (below h=31)
  if (h == 0 || h == 31) {
    int hp = (h == 0) ? 0 : 33;
    for (int r = 0; r < 5; ++r) {
      int idx = r * 256 + tid;
      if (idx < 1088) {
        int gl = idx / 34;
        int col = idx - gl * 34;
        short8 z = {0,0,0,0,0,0,0,0};
        size_t off = ((((size_t)b * 64 + g0 + gl) * 34 + hp) * 34 + col) * 8;
        *reinterpret_cast<short8*>(xm + off) = z;
      }
    }
  }
}

// ---------------- prep 3: scaled weight -> bf16 fragment layout ----------------
__global__ void wpre_kernel(const float* __restrict__ w, unsigned short* __restrict__ wpre) {
  int kb = blockIdx.x & 7;         // grid 64 = [c(8)][kb(8)]
  int c  = blockIdx.x >> 3;
  int co = threadIdx.x;            // 512
  int ci0 = c * 64 + kb * 8;
  const float* wp = w + (size_t)co * 4608 + (size_t)ci0 * 9;   // 72 contiguous floats
  float v[72];
  const f32x4* wp4 = reinterpret_cast<const f32x4*>(wp);
#pragma unroll
  for (int i = 0; i < 18; ++i) {
    f32x4 q = wp4[i];
    v[i * 4 + 0] = q[0]; v[i * 4 + 1] = q[1]; v[i * 4 + 2] = q[2]; v[i * 4 + 3] = q[3];
  }
  const float scale = 1.4731391274719738e-02f;   // (512*9)^-0.5
#pragma unroll
  for (int t = 0; t < 9; ++t) {
    short8 s;
#pragma unroll
    for (int j = 0; j < 8; ++j) s[j] = (short)f2bf(scale * v[j * 9 + t]);
    *reinterpret_cast<short8*>(wpre + ((((size_t)c * 9 + t) * 8 + kb) * 512 + co) * 8) = s;
  }
}

// ---------------- main: implicit-GEMM direct conv ----------------
// grid 256 = [sp(64)=b*8+hg][cog(4)], block 512 = 8 waves (wr,wc 2x2 spatial, kp 2-way K-split)
// A-frags: registers, straight from wpre (L1/L2), double-buffered 1 tap ahead.
//   CRITICAL: buffer selection must be COMPILE-TIME (runtime-indexed ext_vector
//   arrays spill to scratch — R3 was 85x slower from exactly this). The chunk
//   loop is unrolled x2 and the two buffers passed as swapped lvalue refs, so
//   (t&1)?o:e binds statically in the unrolled tap loop.
// B-frags: LDS xbuf, double-buffered per ci-chunk via async global_load_lds.
// xbuf[2][kb=8][rr=6][col=34][8] bf16 = 2 x 26112 B. One barrier per chunk.
__global__ __launch_bounds__(512, 2) void conv_main(
    const unsigned short* __restrict__ wpre,
    const unsigned short* __restrict__ xm,
    const float* __restrict__ rcp,
    const float* __restrict__ bias,
    float* __restrict__ out)
{
  __shared__ __align__(16) char smem[52224];

  int bid = blockIdx.x;
  int cog = bid & 3;
  int sp = bid >> 2;
  int b = sp >> 3;
  int hg = sp & 7;
  int tid = threadIdx.x;
  int lane = tid & 63;
  int wv = tid >> 6;                // 0..7
  int wc = wv & 1;
  int wr = (wv >> 1) & 1;
  int kp = wv >> 2;                 // K-split half
  int l15 = lane & 15, l4 = lane >> 4;

  f32x4 acc[4][4];
#pragma unroll
  for (int i = 0; i < 4; ++i)
#pragma unroll
    for (int j = 0; j < 4; ++j) { f32x4 z = {0.f,0.f,0.f,0.f}; acc[i][j] = z; }

  const unsigned short* xmb = xm + (size_t)b * (64 * 34 * 34 * 8);
  // this thread's A-frag base: element (kb=kp*4+l4, co = cog*128 + wr*64 + l15)
  const unsigned short* wbase =
      wpre + ((size_t)(kp * 4 + l4) * 512 + cog * 128 + wr * 64 + l15) * 8;

  auto stageX = [&](int c, int buf) {
    char* xb = smem + buf * 26112;
#pragma unroll
    for (int r = 0; r < 4; ++r) {
      int idx = r * 512 + tid;                 // [kb(8)][rr(6)][col(34)] = 1632 chunks
      if (idx < 1632) {
        int kb = idx / 204;
        int rem = idx - kb * 204;
        int rr = rem / 34;
        int col = rem - rr * 34;
        const unsigned short* src =
            xmb + (((size_t)(c * 8 + kb) * 34 + hg * 4 + rr) * 34 + col) * 8;
        gload_lds16(src, xb + idx * 16);
      }
    }
  };

  auto loadA = [&](int ct, short8 (&a)[4]) {
    const unsigned short* p = wbase + (size_t)ct * 32768;
#pragma unroll
    for (int mi = 0; mi < 4; ++mi)
      a[mi] = *reinterpret_cast<const short8*>(p + mi * 128);
  };

  short8 A[4], B[4];

  // one ci-chunk = 9 taps; e holds even-linear-tap frags, o odd. 9 is odd, so
  // buffers swap roles every chunk -> caller alternates (A,B),(B,A).
  auto chunk = [&](int c, short8 (&e)[4], short8 (&o)[4]) {
    const char* xb = smem + (c & 1) * 26112;
    if (c < 7) stageX(c + 1, (c + 1) & 1);     // async, drains at chunk-end barrier
#pragma unroll
    for (int t = 0; t < 9; ++t) {
      int ct = c * 9 + t;
      short8 (&cur)[4] = (t & 1) ? o : e;      // compile-time: t is unrolled
      short8 (&nxt)[4] = (t & 1) ? e : o;
      if (ct < 71) loadA(ct + 1, nxt);         // prefetch next tap's A
      int kh = t / 3, kw = t % 3;
#pragma unroll
      for (int nj = 0; nj < 4; ++nj) {
        int row4 = wc * 2 + (nj >> 1);
        int bo = (kp * 4 + l4) * 3264 + (row4 + kh) * 544 + ((nj & 1) * 16 + l15 + kw) * 16;
        short8 bfrag = *reinterpret_cast<const short8*>(xb + bo);
#pragma unroll
        for (int mi = 0; mi < 4; ++mi)
          acc[mi][nj] = __builtin_amdgcn_mfma_f32_16x16x32_bf16(cur[mi], bfrag, acc[mi][nj], 0, 0, 0);
      }
    }
    __syncthreads();
  };

  // prologue
  stageX(0, 0);
  loadA(0, A);
  __syncthreads();

  for (int cc = 0; cc < 8; cc += 2) {
    chunk(cc, A, B);
    chunk(cc + 1, B, A);
  }

  // ---- K-split reduction (kp1 -> LDS -> kp0) ----
#pragma unroll
  for (int p = 0; p < 2; ++p) {
    if (kp == 1 && wr == p) {
#pragma unroll
      for (int mi = 0; mi < 4; ++mi)
#pragma unroll
        for (int nj = 0; nj < 4; ++nj)
          *reinterpret_cast<f32x4*>(smem + wc * 16384 + (mi * 4 + nj) * 1024 + lane * 16) = acc[mi][nj];
    }
    __syncthreads();
    if (kp == 0 && wr == p) {
#pragma unroll
      for (int mi = 0; mi < 4; ++mi)
#pragma unroll
        for (int nj = 0; nj < 4; ++nj) {
          f32x4 v = *reinterpret_cast<const f32x4*>(smem + wc * 16384 + (mi * 4 + nj) * 1024 + lane * 16);
          acc[mi][nj] = acc[mi][nj] + v;
        }
    }
    __syncthreads();
  }

  // ---- epilogue: demod + bias, fp32 NCHW store ----
  if (kp == 0) {
    const float* rcpb = rcp + b * 512;
#pragma unroll
    for (int mi = 0; mi < 4; ++mi) {
      int ob = cog * 128 + wr * 64 + mi * 16 + l4 * 4;
      float rc[4], bi[4];
#pragma unroll
      for (int j = 0; j < 4; ++j) { rc[j] = rcpb[ob + j]; bi[j] = bias[ob + j]; }
#pragma unroll
      for (int nj = 0; nj < 4; ++nj) {
        int row4 = wc * 2 + (nj >> 1);
        int wcol = (nj & 1) * 16 + l15;
        int h = hg * 4 + row4;
#pragma unroll
        for (int j = 0; j < 4; ++j)
          out[(((size_t)b * 512 + ob + j) * 32 + h) * 32 + wcol] = acc[mi][nj][j] * rc[j] + bi[j];
      }
    }
  }
}

extern "C" void kernel_launch(void* const* d_in, const int* in_sizes, int n_in,
                              void* d_out, int out_size, void* d_ws, size_t ws_size,
                              hipStream_t stream) {
  const float* x    = (const float*)d_in[0];
  const float* ys   = (const float*)d_in[1];
  const float* w    = (const float*)d_in[2];
  const float* bias = (const float*)d_in[3];
  float* out = (float*)d_out;
  char* ws = (char*)d_ws;
  float* rcp = (float*)(ws + RCP_OFF);
  unsigned short* wpre = (unsigned short*)(ws + WPRE_OFF);
  unsigned short* xm   = (unsigned short*)(ws + XM_OFF);

  xs_kernel<<<512, 64, 0, stream>>>(w, ys, rcp);
  wpre_kernel<<<64, 512, 0, stream>>>(w, wpre);
  xm_kernel<<<512, 256, 0, stream>>>(x, ys, xm);
  conv_main<<<256, 512, 0, stream>>>(wpre, xm, rcp, bias, out);
}

// Round 5
// 58.491 us; speedup vs baseline: 75.3564x; 1.3278x over previous
//
#include <hip/hip_runtime.h>

typedef __attribute__((ext_vector_type(8))) short short8;
typedef __attribute__((ext_vector_type(4))) float f32x4;

// ---------------- ws layout (bytes) ----------------
// rcp  : float [8][512]                        @ 0         (16384)
// wpre : bf16  [c=8][t=9][kb=8][co=512][8]     @ 16384     (4718592)
// xm   : bf16  [b=8][g=64][hp=34][col=34][8]   @ 4734976   (9469952)  (hp=0 / hp=33 are zero rows)
#define RCP_OFF   0
#define WPRE_OFF  16384
#define XM_OFF    4734976

__device__ __forceinline__ unsigned short f2bf(float f) {
  unsigned int u = __float_as_uint(f);
  u += 0x7FFFu + ((u >> 16) & 1u);       // round-to-nearest-even
  return (unsigned short)(u >> 16);
}

__device__ __forceinline__ void gload_lds16(const void* g, void* l) {
  __builtin_amdgcn_global_load_lds(
      (__attribute__((address_space(1))) void*)g,
      (__attribute__((address_space(3))) void*)l, 16, 0, 0);
}

// ---------------- fused prep: xm (blocks 0-511) | wpre (512-639) | xs (640-767) ----------------
__global__ __launch_bounds__(256) void prep_kernel(
    const float* __restrict__ x, const float* __restrict__ ys,
    const float* __restrict__ w,
    unsigned short* __restrict__ xm, unsigned short* __restrict__ wpre,
    float* __restrict__ rcp) {
  int bid = blockIdx.x;
  int tid = threadIdx.x;

  if (bid < 512) {
    // ---- xm: modulated x -> bf16, channel-grouped, padded h & w ----
    int half = bid & 1;
    int h = (bid >> 1) & 31;
    int b = bid >> 6;
    __shared__ float tile[256][33];
    int ci0 = half * 256;
#pragma unroll
    for (int r = 0; r < 32; ++r) {
      int ci = r * 8 + (tid >> 5);
      int wcol = tid & 31;
      float v = x[(((size_t)b * 512 + ci0 + ci) * 32 + h) * 32 + wcol];
      tile[ci][wcol] = v * ys[b * 512 + ci0 + ci];
    }
    __syncthreads();
    int g0 = half * 32;
    for (int r = 0; r < 5; ++r) {
      int idx = r * 256 + tid;                     // [gl(32)][col(34)]
      if (idx < 1088) {
        int gl = idx / 34;
        int col = idx - gl * 34;
        short8 v = {0,0,0,0,0,0,0,0};
        if (col != 0 && col != 33) {
          int wcol = col - 1;
#pragma unroll
          for (int j = 0; j < 8; ++j)
            v[j] = (short)f2bf(tile[gl * 8 + j][wcol]);
        }
        size_t off = ((((size_t)b * 64 + g0 + gl) * 34 + (h + 1)) * 34 + col) * 8;
        *reinterpret_cast<short8*>(xm + off) = v;
      }
    }
    if (h == 0 || h == 31) {
      int hp = (h == 0) ? 0 : 33;
      for (int r = 0; r < 5; ++r) {
        int idx = r * 256 + tid;
        if (idx < 1088) {
          int gl = idx / 34;
          int col = idx - gl * 34;
          short8 z = {0,0,0,0,0,0,0,0};
          size_t off = ((((size_t)b * 64 + g0 + gl) * 34 + hp) * 34 + col) * 8;
          *reinterpret_cast<short8*>(xm + off) = z;
        }
      }
    }
  } else if (bid < 640) {
    // ---- wpre: scaled weight -> bf16 fragment layout ----
    int pid = bid - 512;             // [c(8)][kb(8)][coh(2)]
    int coh = pid & 1;
    int kb = (pid >> 1) & 7;
    int c = pid >> 4;
    int co = coh * 256 + tid;
    int ci0 = c * 64 + kb * 8;
    const float* wp = w + (size_t)co * 4608 + (size_t)ci0 * 9;   // 72 contiguous floats
    float v[72];
    const f32x4* wp4 = reinterpret_cast<const f32x4*>(wp);
#pragma unroll
    for (int i = 0; i < 18; ++i) {
      f32x4 q = wp4[i];
      v[i * 4 + 0] = q[0]; v[i * 4 + 1] = q[1]; v[i * 4 + 2] = q[2]; v[i * 4 + 3] = q[3];
    }
    const float scale = 1.4731391274719738e-02f;   // (512*9)^-0.5
#pragma unroll
    for (int t = 0; t < 9; ++t) {
      short8 s;
#pragma unroll
      for (int j = 0; j < 8; ++j) s[j] = (short)f2bf(scale * v[j * 9 + t]);
      *reinterpret_cast<short8*>(wpre + ((((size_t)c * 9 + t) * 8 + kb) * 512 + co) * 8) = s;
    }
  } else {
    // ---- xs: demod rcp[b][o], one wave per o ----
    int pid = bid - 640;
    int wv = tid >> 6;
    int lane = tid & 63;
    int o = pid * 4 + wv;
    const float* wp = w + (size_t)o * 4608 + (size_t)lane * 72;  // 8 ci x 9 taps
    const float scale2 = 1.0f / 4608.0f;
    float w2[8];
#pragma unroll
    for (int j = 0; j < 8; ++j) {
      float s = 0.f;
#pragma unroll
      for (int k = 0; k < 9; ++k) { float vv = wp[j * 9 + k]; s += vv * vv; }
      w2[j] = s * scale2;
    }
#pragma unroll
    for (int b = 0; b < 8; ++b) {
      float p = 0.f;
#pragma unroll
      for (int j = 0; j < 8; ++j) {
        float y = ys[b * 512 + lane * 8 + j];
        p += y * y * w2[j];
      }
#pragma unroll
      for (int off = 32; off > 0; off >>= 1) p += __shfl_down(p, off);
      if (lane == 0) rcp[b * 512 + o] = 1.0f / sqrtf(p + 1e-8f);
    }
  }
}

// ---------------- main: implicit-GEMM direct conv ----------------
// grid 256, block 512 = 8 waves (wr,wc 2x2 spatial, kp 2-way K-split).
// XCD swizzle: bid&7 = XCD (round-robin dispatch). Each XCD pair owns one cog
// -> its 1.18 MB wpre slice stays L2-resident (R4 spilled to L3: 45.6us).
// A-frags: registers from wpre, prefetch depth 2 via 3 compile-time-rotated
// buffers (t%3 static; runtime indexing => scratch, R3 = 85x slower).
// B-frags: LDS xbuf, dbuf per ci-chunk via global_load_lds.
// Chunk barrier = counted s_waitcnt vmcnt(8) + raw s_barrier: keeps the 2
// newest A-tap prefetches in flight (8 loads) while guaranteeing stageX done.
__global__ __launch_bounds__(512, 1) void conv_main(
    const unsigned short* __restrict__ wpre,
    const unsigned short* __restrict__ xm,
    const float* __restrict__ rcp,
    const float* __restrict__ bias,
    float* __restrict__ out)
{
  __shared__ __align__(16) char smem[52224];

  int bid = blockIdx.x;
  int xcd = bid & 7;
  int j0 = bid >> 3;                // 0..31 within XCD
  int cog = xcd >> 1;               // 2 XCDs per cog
  int sp = (xcd & 1) * 32 + j0;
  int b = sp >> 3;
  int hg = sp & 7;
  int tid = threadIdx.x;
  int lane = tid & 63;
  int wv = tid >> 6;                // 0..7
  int wc = wv & 1;
  int wr = (wv >> 1) & 1;
  int kp = wv >> 2;                 // K-split half
  int l15 = lane & 15, l4 = lane >> 4;

  f32x4 acc[4][4];
#pragma unroll
  for (int i = 0; i < 4; ++i)
#pragma unroll
    for (int jj = 0; jj < 4; ++jj) { f32x4 z = {0.f,0.f,0.f,0.f}; acc[i][jj] = z; }

  const unsigned short* xmb = xm + (size_t)b * (64 * 34 * 34 * 8);
  // this thread's A-frag base: element (kb=kp*4+l4, co = cog*128 + wr*64 + l15)
  const unsigned short* wbase =
      wpre + ((size_t)(kp * 4 + l4) * 512 + cog * 128 + wr * 64 + l15) * 8;

  auto stageX = [&](int c, int buf) {
    char* xb = smem + buf * 26112;
#pragma unroll
    for (int r = 0; r < 4; ++r) {
      int idx = r * 512 + tid;                 // [kb(8)][rr(6)][col(34)] = 1632 chunks
      if (idx < 1632) {
        int kb = idx / 204;
        int rem = idx - kb * 204;
        int rr = rem / 34;
        int col = rem - rr * 34;
        const unsigned short* src =
            xmb + (((size_t)(c * 8 + kb) * 34 + hg * 4 + rr) * 34 + col) * 8;
        gload_lds16(src, xb + idx * 16);
      }
    }
  };

  auto loadA = [&](int ct, short8 (&a)[4]) {
    const unsigned short* p = wbase + (size_t)ct * 32768;
#pragma unroll
    for (int mi = 0; mi < 4; ++mi)
      a[mi] = *reinterpret_cast<const short8*>(p + mi * 128);
  };

  short8 X[4], Y[4], Z[4];          // depth-2 A pipeline, roles rotate by t%3

  // prologue
  stageX(0, 0);
  loadA(0, X);
  loadA(1, Y);
  __syncthreads();

  for (int c = 0; c < 8; ++c) {
    const char* xb = smem + (c & 1) * 26112;
    if (c < 7) stageX(c + 1, (c + 1) & 1);     // async, verified done at chunk barrier
#pragma unroll
    for (int t = 0; t < 9; ++t) {
      int ct = c * 9 + t;
      short8 (&cur)[4] = (t % 3 == 0) ? X : ((t % 3 == 1) ? Y : Z);   // static: t unrolled
      short8 (&nxt)[4] = (t % 3 == 0) ? Z : ((t % 3 == 1) ? X : Y);   // (t+2)%3
      if (ct < 70) loadA(ct + 2, nxt);         // prefetch 2 taps ahead
      int kh = t / 3, kw = t % 3;
#pragma unroll
      for (int nj = 0; nj < 4; ++nj) {
        int row4 = wc * 2 + (nj >> 1);
        int bo = (kp * 4 + l4) * 3264 + (row4 + kh) * 544 + ((nj & 1) * 16 + l15 + kw) * 16;
        short8 bfrag = *reinterpret_cast<const short8*>(xb + bo);
#pragma unroll
        for (int mi = 0; mi < 4; ++mi)
          acc[mi][nj] = __builtin_amdgcn_mfma_f32_16x16x32_bf16(cur[mi], bfrag, acc[mi][nj], 0, 0, 0);
      }
    }
    if (c < 7) {
      // counted drain: stageX(c+1) (old) must be done; the 8 newest vmem ops
      // (A prefetches for the next 2 taps) may stay in flight.
      asm volatile("s_waitcnt vmcnt(8)" ::: "memory");
      __builtin_amdgcn_s_barrier();
      asm volatile("" ::: "memory");
    }
  }
  __syncthreads();                  // full drain before smem reuse

  // ---- K-split reduction (kp1 -> LDS -> kp0) ----
#pragma unroll
  for (int p = 0; p < 2; ++p) {
    if (kp == 1 && wr == p) {
#pragma unroll
      for (int mi = 0; mi < 4; ++mi)
#pragma unroll
        for (int nj = 0; nj < 4; ++nj)
          *reinterpret_cast<f32x4*>(smem + wc * 16384 + (mi * 4 + nj) * 1024 + lane * 16) = acc[mi][nj];
    }
    __syncthreads();
    if (kp == 0 && wr == p) {
#pragma unroll
      for (int mi = 0; mi < 4; ++mi)
#pragma unroll
        for (int nj = 0; nj < 4; ++nj) {
          f32x4 v = *reinterpret_cast<const f32x4*>(smem + wc * 16384 + (mi * 4 + nj) * 1024 + lane * 16);
          acc[mi][nj] = acc[mi][nj] + v;
        }
    }
    __syncthreads();
  }

  // ---- epilogue: demod + bias, fp32 NCHW store ----
  if (kp == 0) {
    const float* rcpb = rcp + b * 512;
#pragma unroll
    for (int mi = 0; mi < 4; ++mi) {
      int ob = cog * 128 + wr * 64 + mi * 16 + l4 * 4;
      float rc[4], bi[4];
#pragma unroll
      for (int jj = 0; jj < 4; ++jj) { rc[jj] = rcpb[ob + jj]; bi[jj] = bias[ob + jj]; }
#pragma unroll
      for (int nj = 0; nj < 4; ++nj) {
        int row4 = wc * 2 + (nj >> 1);
        int wcol = (nj & 1) * 16 + l15;
        int h = hg * 4 + row4;
#pragma unroll
        for (int jj = 0; jj < 4; ++jj)
          out[(((size_t)b * 512 + ob + jj) * 32 + h) * 32 + wcol] = acc[mi][nj][jj] * rc[jj] + bi[jj];
      }
    }
  }
}

extern "C" void kernel_launch(void* const* d_in, const int* in_sizes, int n_in,
                              void* d_out, int out_size, void* d_ws, size_t ws_size,
                              hipStream_t stream) {
  const float* x    = (const float*)d_in[0];
  const float* ys   = (const float*)d_in[1];
  const float* w    = (const float*)d_in[2];
  const float* bias = (const float*)d_in[3];
  float* out = (float*)d_out;
  char* ws = (char*)d_ws;
  float* rcp = (float*)(ws + RCP_OFF);
  unsigned short* wpre = (unsigned short*)(ws + WPRE_OFF);
  unsigned short* xm   = (unsigned short*)(ws + XM_OFF);

  prep_kernel<<<768, 256, 0, stream>>>(x, ys, w, xm, wpre, rcp);
  conv_main<<<256, 512, 0, stream>>>(wpre, xm, rcp, bias, out);
}